// Round 12
// baseline (231.070 us; speedup 1.0000x reference)
//
#include <hip/hip_runtime.h>
#include <hip/hip_bf16.h>

#define Bb 8
#define Cch 256
#define Nn 2048
#define Mm 2048
#define KKEEP 1638
#define RANK 410   /* Nn - KKEEP, 0-indexed ascending rank of threshold */
#define HGROUPS 4
#define HPITCH 260 /* 4 sub-hists, 4-bank shift/group: cross-group conflict-free */
#define SPLITK4 4

typedef __hip_bfloat16 bf16;
typedef __attribute__((ext_vector_type(8))) short bf16x8;
typedef __attribute__((ext_vector_type(4))) float f32x4;
typedef unsigned int u32;
typedef unsigned short u16;

__device__ __forceinline__ void gload_lds16(const void* g, void* l) {
  __builtin_amdgcn_global_load_lds((const __attribute__((address_space(1))) u32*)g,
                                   (__attribute__((address_space(3))) u32*)l, 16, 0, 0);
}

__device__ __forceinline__ u16 f2bf(float x) {
  bf16 t = __float2bfloat16(x);
  u16 r; __builtin_memcpy(&r, &t, 2);
  return r;
}

// ---------------- norms: inv[b*NN+n] = 1/max(||x[b,:,n]||, 1e-12) ----------
__global__ __launch_bounds__(256) void norm_kernel(const float* __restrict__ t,
                                                   float* __restrict__ inv) {
  int idx = blockIdx.x * 256 + threadIdx.x;          // b*Nn + n
  int b = idx >> 11, n = idx & (Nn - 1);
  const float* p = t + (size_t)b * Cch * Nn + n;
  float s = 0.f;
  #pragma unroll 4
  for (int c = 0; c < Cch; ++c) { float v = p[(size_t)c * Nn]; s += v * v; }
  inv[idx] = 1.f / fmaxf(sqrtf(s), 1e-12f);
}

// ------------- transpose+scale+bf16: out[b][n][c] = bf16(in[b][c][n]*inv[b][n])
// Optionally also emits raw bf16 copy in original [b][c][n] layout (rawb).
__global__ __launch_bounds__(256) void transpose_scale(const float* __restrict__ in,
                                                       const float* __restrict__ inv,
                                                       bf16* __restrict__ outp,
                                                       bf16* __restrict__ rawb) {
  __shared__ float tile[32][33];
  int b = blockIdx.z;
  int n0 = blockIdx.x * 32, c0 = blockIdx.y * 32;
  int tx = threadIdx.x, ty = threadIdx.y;
  const float* src = in + (size_t)b * Cch * Nn;
  #pragma unroll
  for (int i = 0; i < 32; i += 8) {
    float v = src[(size_t)(c0 + ty + i) * Nn + n0 + tx];
    tile[ty + i][tx] = v;
    if (rawb) rawb[(size_t)b * Cch * Nn + (size_t)(c0 + ty + i) * Nn + n0 + tx] = __float2bfloat16(v);
  }
  __syncthreads();
  bf16* dst = outp + (size_t)b * Nn * Cch;
  #pragma unroll
  for (int i = 0; i < 32; i += 8) {
    int n = n0 + ty + i;
    float sc = inv[(b << 11) + n];
    dst[(size_t)n * Cch + c0 + tx] = __float2bfloat16(tile[tx][ty + i] * sc);
  }
}

// ------------- zero the BN accumulator (512 floats) ------------------------
__global__ void zero_bnsum(float* p) { p[threadIdx.x] = 0.f; }

// ------------- m97-style 128x128 bf16 MFMA GEMM (gemm1), C = A * Bt^T ------
__global__ __launch_bounds__(256) void gemm_bt1(const bf16* __restrict__ A,
                                                const bf16* __restrict__ Bt,
                                                bf16* __restrict__ Cout,
                                                int Mrows, int Ncols, int K) {
  __shared__ bf16 aT[128 * 32];
  __shared__ bf16 bT[128 * 32];
  const int b = blockIdx.z;
  const int m0 = blockIdx.x * 128;
  const int n0 = blockIdx.y * 128;
  const bf16* Ab = A + (size_t)b * Mrows * K;
  const bf16* Bbp = Bt + (size_t)b * Ncols * K;
  const int tid = threadIdx.x;
  const int lane = tid & 63;
  const int wave = tid >> 6;
  const int wr = wave >> 1, wc = wave & 1;

  f32x4 acc[4][4];
  #pragma unroll
  for (int i = 0; i < 4; i++)
    #pragma unroll
    for (int j = 0; j < 4; j++) acc[i][j] = (f32x4){0.f, 0.f, 0.f, 0.f};

  const int srow = tid >> 2;
  const int scol = (tid & 3) * 8;
  const bf16* gA0 = Ab + (size_t)(m0 + srow) * K + scol;
  const bf16* gB0 = Bbp + (size_t)(n0 + srow) * K + scol;
  bf16* lA = aT + wave * 512;   // wave-uniform LDS base (lane*16B auto-added)
  bf16* lB = bT + wave * 512;

  const int fm = lane & 15;
  const int kb = (lane >> 4) * 8;

  for (int kt = 0; kt < K; kt += 32) {
    gload_lds16(gA0 + kt, lA);
    gload_lds16(gA0 + (size_t)64 * K + kt, lA + 2048);
    gload_lds16(gB0 + kt, lB);
    gload_lds16(gB0 + (size_t)64 * K + kt, lB + 2048);
    __syncthreads();
    bf16x8 af[4], bf_[4];
    #pragma unroll
    for (int mf = 0; mf < 4; mf++)
      af[mf] = *(const bf16x8*)&aT[(wr * 64 + mf * 16 + fm) * 32 + kb];
    #pragma unroll
    for (int nf = 0; nf < 4; nf++)
      bf_[nf] = *(const bf16x8*)&bT[(wc * 64 + nf * 16 + fm) * 32 + kb];
    #pragma unroll
    for (int mf = 0; mf < 4; mf++)
      #pragma unroll
      for (int nf = 0; nf < 4; nf++)
        acc[mf][nf] = __builtin_amdgcn_mfma_f32_16x16x32_bf16(af[mf], bf_[nf], acc[mf][nf], 0, 0, 0);
    __syncthreads();
  }

  const int orow = (lane >> 4) * 4;
  const int ocol = lane & 15;
  bf16* Cb = Cout + (size_t)b * Mrows * Ncols;
  #pragma unroll
  for (int mf = 0; mf < 4; mf++)
    #pragma unroll
    for (int nf = 0; nf < 4; nf++)
      #pragma unroll
      for (int r = 0; r < 4; r++) {
        int gm = m0 + wr * 64 + mf * 16 + orow + r;
        int gn = n0 + wc * 64 + nf * 16 + ocol;
        Cb[(size_t)gm * Ncols + gn] = __float2bfloat16(acc[mf][nf][r]);
      }
}

// ---- wave-level inclusive scan over 64 lanes ------------------------------
__device__ __forceinline__ u32 wave_incl_scan(u32 v, int lane) {
  #pragma unroll
  for (int off = 1; off < 64; off <<= 1) {
    u32 t = __shfl_up(v, off, 64);
    if (lane >= off) v += t;
  }
  return v;
}

// ------------- per-row top-k SELECT (no S rewrite) -------------------------
// Computes per row: threshold float tf, inv_denom, tstar = global index of
// the last KEPT tie (-1 if none). gemm2 applies the mask+softmax on the fly:
// keep iff f > tf || (f == tf && n <= tstar). Eliminates the 67MB S
// write-back and the whole mask/pack phase of the old row_topk.
__global__ __launch_bounds__(256) void select_topk(const bf16* __restrict__ S,
                                                   float4* __restrict__ rowp) {
  const int lane = threadIdx.x & 63;
  const int wv = threadIdx.x >> 6;                 // 0..3
  const int rowIdx = blockIdx.x * 4 + wv;
  const bf16* row = S + (size_t)rowIdx * Nn;
  __shared__ u32 hist_s[4][HGROUPS * HPITCH];      // 4 x 4160B
  u32* hist = hist_s[wv];                          // wave-private
  u32* myhist = hist + (lane & (HGROUPS - 1)) * HPITCH;

  // ---- load: slot k holds global elems k*512 + lane*8 .. +7 ----
  uint4 rw[4];
  #pragma unroll
  for (int k = 0; k < 4; k++) rw[k] = ((const uint4*)row)[k * 64 + lane];

  u16 key[32];
  float se = 0.f;
  #pragma unroll
  for (int k = 0; k < 4; k++) {
    u32 wd[4] = {rw[k].x, rw[k].y, rw[k].z, rw[k].w};
    #pragma unroll
    for (int j = 0; j < 4; j++) {
      u16 a = (u16)(wd[j] & 0xFFFF), b = (u16)(wd[j] >> 16);
      int i0 = k * 8 + 2 * j;
      key[i0]     = (a & 0x8000) ? (u16)(~a) : (u16)(a | 0x8000);
      key[i0 + 1] = (b & 0x8000) ? (u16)(~b) : (u16)(b | 0x8000);
      u32 ba = ((u32)a) << 16, bb = ((u32)b) << 16;
      float fa, fb; __builtin_memcpy(&fa, &ba, 4); __builtin_memcpy(&fb, &bb, 4);
      se += __expf(fa) + __expf(fb);   // no max pass: |S| <= ~1.01 (cosine)
    }
  }
  #pragma unroll
  for (int off = 32; off > 0; off >>= 1) se += __shfl_xor(se, off, 64);
  float inv_denom = 1.f / se;

  // ---- radix pass 1: histogram of high byte ----
  #pragma unroll
  for (int i = 0; i < 16; i++) hist[i * 64 + lane] = 0;
  if (lane < HGROUPS * HPITCH - 1024) hist[1024 + lane] = 0;
  __threadfence_block();
  #pragma unroll
  for (int i = 0; i < 32; i++) atomicAdd(&myhist[key[i] >> 8], 1u);
  __threadfence_block();
  u32 h[4], c[4];
  h[0] = h[1] = h[2] = h[3] = 0;
  #pragma unroll
  for (int gg = 0; gg < HGROUPS; gg++) {
    uint4 v = *(const uint4*)&hist[gg * HPITCH + lane * 4];
    h[0] += v.x; h[1] += v.y; h[2] += v.z; h[3] += v.w;
  }
  c[0] = h[0]; c[1] = c[0] + h[1]; c[2] = c[1] + h[2]; c[3] = c[2] + h[3];
  u32 inclTot = wave_incl_scan(c[3], lane);
  u32 pre = inclTot - c[3];                         // exclusive prefix of my 4 bins
  u32 binsel = 0xFFFFFFFFu, belowv = 0;
  #pragma unroll
  for (int i = 0; i < 4; i++) {
    u32 incl = pre + c[i];
    if (incl > (u32)RANK && incl - h[i] <= (u32)RANK) { binsel = lane * 4 + i; belowv = incl - h[i]; }
  }
  unsigned long long mk = __ballot(binsel != 0xFFFFFFFFu);
  int src = __ffsll(mk) - 1;
  u32 b1 = __shfl(binsel, src, 64);
  u32 below = __shfl(belowv, src, 64);

  // ---- radix pass 2: low byte among keys in bucket b1 ----
  #pragma unroll
  for (int i = 0; i < 16; i++) hist[i * 64 + lane] = 0;
  if (lane < HGROUPS * HPITCH - 1024) hist[1024 + lane] = 0;
  __threadfence_block();
  #pragma unroll
  for (int i = 0; i < 32; i++)
    if ((u32)(key[i] >> 8) == b1) atomicAdd(&myhist[key[i] & 0xFF], 1u);
  __threadfence_block();
  h[0] = h[1] = h[2] = h[3] = 0;
  #pragma unroll
  for (int gg = 0; gg < HGROUPS; gg++) {
    uint4 v = *(const uint4*)&hist[gg * HPITCH + lane * 4];
    h[0] += v.x; h[1] += v.y; h[2] += v.z; h[3] += v.w;
  }
  c[0] = h[0]; c[1] = c[0] + h[1]; c[2] = c[1] + h[2]; c[3] = c[2] + h[3];
  inclTot = wave_incl_scan(c[3], lane);
  pre = inclTot - c[3];
  binsel = 0xFFFFFFFFu; u32 totv = 0;
  #pragma unroll
  for (int i = 0; i < 4; i++) {
    u32 incl = below + pre + c[i];
    if (incl > (u32)RANK && incl - h[i] <= (u32)RANK) { binsel = lane * 4 + i; totv = incl; }
  }
  mk = __ballot(binsel != 0xFFFFFFFFu);
  src = __ffsll(mk) - 1;
  u32 lowb = __shfl(binsel, src, 64);
  u32 totalLE = __shfl(totv, src, 64);              // #keys <= tkey
  u16 tkey = (u16)((b1 << 8) | lowb);
  int keepEq = KKEEP - (Nn - (int)totalLE);         // ties kept, lowest global index first

  // ---- tie ordering: find global index of the (keepEq-1)-th tie ----
  int eqk[4];
  #pragma unroll
  for (int k = 0; k < 4; k++) {
    int c2 = 0;
    #pragma unroll
    for (int j = 0; j < 8; j++) c2 += (key[k * 8 + j] == tkey);
    eqk[k] = c2;
  }
  int eqbase[4]; int running = 0;
  #pragma unroll
  for (int k = 0; k < 4; k++) {
    u32 inclL = wave_incl_scan((u32)eqk[k], lane);
    int waveTot = __shfl((int)inclL, 63, 64);
    eqbase[k] = running + (int)inclL - eqk[k];
    running += waveTot;
  }
  int tstar = -1;
  #pragma unroll
  for (int k = 0; k < 4; k++) {
    int eqs = eqbase[k];
    #pragma unroll
    for (int j = 0; j < 8; j++) {
      if (key[k * 8 + j] == tkey) {
        if (eqs == keepEq - 1) tstar = k * 512 + lane * 8 + j;
        eqs++;
      }
    }
  }
  #pragma unroll
  for (int off = 32; off > 0; off >>= 1) tstar = max(tstar, __shfl_xor(tstar, off, 64));

  if (lane == 0) {
    u32 ub = (tkey & 0x8000) ? ((u32)tkey ^ 0x8000u) : (u32)(u16)(~tkey);
    u32 fb = ub << 16;
    float tf; __builtin_memcpy(&tf, &fb, 4);
    rowp[rowIdx] = make_float4(tf, inv_denom, __int_as_float(tstar), 0.f);
  }
}

// ------------- gemm2 with fused on-the-fly softmax/top-k mask --------------
// out_part = xb * softmaxmask(S)^T. Wave-async: 4 waves, each owns a 64x64
// tile (wave w covers channels w*64..+63 -> block covers all 256 channels,
// so each S panel is read ONCE per (n-tile, ks)). Raw S staged to LDS; the
// softmax transform (exp * inv, mask via tf/tstar) runs between ds_read and
// MFMA — VALU that lands in the formerly-idle stall windows.
// Split-K=4 bf16 partials; grid (8, 32*4): blockIdx.x = batch pins XCD.
__global__ __launch_bounds__(256) void gemm2_wave(const bf16* __restrict__ A,
                                                  const bf16* __restrict__ S,
                                                  const float4* __restrict__ rowp,
                                                  bf16* __restrict__ part) {
  constexpr int KS = Nn / SPLITK4;           // 512
  constexpr int NT = KS / 32;                // 16 steps
  constexpr int numNT = Mm / 64;             // 32 n-tiles
  __shared__ bf16 aW[4][64 * 32];
  __shared__ bf16 bW[4][64 * 32];
  const int b = blockIdx.x;                  // XCD = dispatch_id % 8 = batch
  int yy = blockIdx.y;
  int nt = yy % numNT, ks = yy / numNT;
  int n0 = nt * 64;
  const int lane = threadIdx.x & 63;
  const int w = threadIdx.x >> 6;
  const int srow = lane >> 2;                // 16 rows per gload
  const int scol = (lane & 3) * 8;
  const int kOff = ks * KS;
  const bf16* gA = A + (size_t)b * Cch * Nn + (size_t)(w * 64 + srow) * Nn + kOff + scol;
  const bf16* gB = S + (size_t)b * Mm * Nn + (size_t)(n0 + srow) * Nn + kOff + scol;
  const int fm = lane & 15;
  const int kb = (lane >> 4) * 8;

  // per-lane row params for S rows n0 + nf*16 + fm
  float tf[4], inv[4]; int ts[4];
  #pragma unroll
  for (int nf = 0; nf < 4; nf++) {
    float4 q = rowp[(size_t)b * Mm + n0 + nf * 16 + fm];
    tf[nf] = q.x; inv[nf] = q.y; ts[nf] = __float_as_int(q.z);
  }

  f32x4 acc[4][4];
  #pragma unroll
  for (int i = 0; i < 4; i++)
    #pragma unroll
    for (int j = 0; j < 4; j++) acc[i][j] = (f32x4){0.f, 0.f, 0.f, 0.f};

  bf16* lA = &aW[w][0];                      // wave-uniform LDS bases
  bf16* lB = &bW[w][0];

  for (int t = 0; t < NT; ++t) {
    int kt = t * 32;
    #pragma unroll
    for (int i = 0; i < 4; i++)
      gload_lds16(gA + (size_t)(i * 16) * Nn + kt, lA + i * 16 * 32);
    #pragma unroll
    for (int i = 0; i < 4; i++)
      gload_lds16(gB + (size_t)(i * 16) * Nn + kt, lB + i * 16 * 32);
    asm volatile("s_waitcnt vmcnt(0)" ::: "memory");
    bf16x8 af[4], bf_[4];
    #pragma unroll
    for (int mf = 0; mf < 4; mf++)
      af[mf] = *(const bf16x8*)&aW[w][(mf * 16 + fm) * 32 + kb];
    #pragma unroll
    for (int nf = 0; nf < 4; nf++) {
      uint4 braw = *(const uint4*)&bW[w][(nf * 16 + fm) * 32 + kb];
      u32 wd[4] = {braw.x, braw.y, braw.z, braw.w};
      int nbase = kOff + kt + kb;
      union { u16 h[8]; bf16x8 v; } pk;
      #pragma unroll
      for (int j = 0; j < 4; j++) {
        u32 lo = wd[j] << 16, hi = wd[j] & 0xFFFF0000u;
        float f0, f1;
        __builtin_memcpy(&f0, &lo, 4);
        __builtin_memcpy(&f1, &hi, 4);
        float p0 = __expf(f0) * inv[nf];
        float p1 = __expf(f1) * inv[nf];
        int ni0 = nbase + 2 * j, ni1 = nbase + 2 * j + 1;
        bool k0 = (f0 > tf[nf]) || (f0 == tf[nf] && ni0 <= ts[nf]);
        bool k1 = (f1 > tf[nf]) || (f1 == tf[nf] && ni1 <= ts[nf]);
        pk.h[2 * j]     = f2bf(k0 ? p0 : 0.f);
        pk.h[2 * j + 1] = f2bf(k1 ? p1 : 0.f);
      }
      bf_[nf] = pk.v;
    }
    #pragma unroll
    for (int mf = 0; mf < 4; mf++)
      #pragma unroll
      for (int nf = 0; nf < 4; nf++)
        acc[mf][nf] = __builtin_amdgcn_mfma_f32_16x16x32_bf16(af[mf], bf_[nf], acc[mf][nf], 0, 0, 0);
  }

  const int orow = (lane >> 4) * 4;
  const int ocol = lane & 15;
  bf16* Pb = part + ((size_t)ks * Bb + b) * Cch * Mm;
  #pragma unroll
  for (int mf = 0; mf < 4; mf++)
    #pragma unroll
    for (int nf = 0; nf < 4; nf++)
      #pragma unroll
      for (int r = 0; r < 4; r++) {
        int gm = w * 64 + mf * 16 + orow + r;
        int gn = n0 + nf * 16 + ocol;
        Pb[(size_t)gm * Mm + gn] = __float2bfloat16(acc[mf][nf][r]);
      }
}

// ------------- combine split-K bf16 partials: leaky + BN stats + out -------
__global__ __launch_bounds__(256) void combine_bn(const bf16* __restrict__ part,
                                                  float* __restrict__ outp,
                                                  float* __restrict__ bnsum) {
  int bc = blockIdx.x;                       // b*Cch + c
  int tid = threadIdx.x;
  size_t sl = (size_t)Bb * Cch * Mm;
  uint4 a[SPLITK4];
  #pragma unroll
  for (int s = 0; s < SPLITK4; s++)
    a[s] = ((const uint4*)(part + s * sl + (size_t)bc * Mm))[tid];
  float v[8];
  #pragma unroll
  for (int j = 0; j < 4; j++) {
    u32 w0 = ((const u32*)&a[0])[j], w1 = ((const u32*)&a[1])[j];
    u32 w2 = ((const u32*)&a[2])[j], w3 = ((const u32*)&a[3])[j];
    u32 lo = (w0 << 16), hi = (w0 & 0xFFFF0000u);
    float f0, f1; __builtin_memcpy(&f0, &lo, 4); __builtin_memcpy(&f1, &hi, 4);
    u32 lo1 = (w1 << 16), hi1 = (w1 & 0xFFFF0000u);
    float g0, g1; __builtin_memcpy(&g0, &lo1, 4); __builtin_memcpy(&g1, &hi1, 4);
    u32 lo2 = (w2 << 16), hi2 = (w2 & 0xFFFF0000u);
    float h0, h1; __builtin_memcpy(&h0, &lo2, 4); __builtin_memcpy(&h1, &hi2, 4);
    u32 lo3 = (w3 << 16), hi3 = (w3 & 0xFFFF0000u);
    float i0, i1; __builtin_memcpy(&i0, &lo3, 4); __builtin_memcpy(&i1, &hi3, 4);
    v[2 * j]     = f0 + g0 + h0 + i0;
    v[2 * j + 1] = f1 + g1 + h1 + i1;
  }
  float s = 0.f, ss = 0.f;
  #pragma unroll
  for (int j = 0; j < 8; j++) {
    float y = v[j];
    y = y >= 0.f ? y : 0.01f * y;
    v[j] = y;
    s += y; ss += y * y;
  }
  float4* po = (float4*)(outp + (size_t)bc * Mm);
  po[tid * 2]     = make_float4(v[0], v[1], v[2], v[3]);
  po[tid * 2 + 1] = make_float4(v[4], v[5], v[6], v[7]);
  __shared__ float r1[256], r2[256];
  r1[tid] = s; r2[tid] = ss; __syncthreads();
  for (int k = 128; k > 0; k >>= 1) {
    if (tid < k) { r1[tid] += r1[tid + k]; r2[tid] += r2[tid + k]; }
    __syncthreads();
  }
  if (tid == 0) {
    int c = bc & (Cch - 1);
    atomicAdd(&bnsum[c], r1[0]);
    atomicAdd(&bnsum[Cch + c], r2[0]);
  }
}

// ------------- BN finalize: scale/shift per channel ------------------------
__global__ __launch_bounds__(256) void bn_finalize(const float* __restrict__ bnsum,
                                                   const float* __restrict__ bnw,
                                                   const float* __restrict__ bnb,
                                                   float* __restrict__ scsh) {
  int c = threadIdx.x;
  float cnt = (float)(Bb * Mm);
  float mean = bnsum[c] / cnt;
  float var = bnsum[Cch + c] / cnt - mean * mean;
  float scale = bnw[c] / sqrtf(var + 1e-5f);
  scsh[c * 2] = scale;
  scsh[c * 2 + 1] = bnb[c] - mean * scale;
}

// ------------- final: out = (y*scale+shift)*gamma + tg --------------------
__global__ __launch_bounds__(256) void final_kernel(float* io, const float* __restrict__ tg,
                                                    const float* __restrict__ scsh,
                                                    const float* __restrict__ gamma) {
  size_t n4 = (size_t)Bb * Cch * Mm / 4;
  float g = gamma[0];
  size_t stride = (size_t)gridDim.x * 256;
  for (size_t i = (size_t)blockIdx.x * 256 + threadIdx.x; i < n4; i += stride) {
    int c = (int)((i * 4 / Mm) % Cch);
    float4 v = ((const float4*)io)[i];
    float4 t = ((const float4*)tg)[i];
    float sc = scsh[c * 2], sh = scsh[c * 2 + 1];
    v.x = (v.x * sc + sh) * g + t.x;
    v.y = (v.y * sc + sh) * g + t.y;
    v.z = (v.z * sc + sh) * g + t.z;
    v.w = (v.w * sc + sh) * g + t.w;
    ((float4*)io)[i] = v;
  }
}

extern "C" void kernel_launch(void* const* d_in, const int* in_sizes, int n_in,
                              void* d_out, int out_size, void* d_ws, size_t ws_size,
                              hipStream_t stream) {
  (void)in_sizes; (void)n_in; (void)out_size; (void)ws_size;
  const float* x   = (const float*)d_in[0];
  const float* tg  = (const float*)d_in[1];
  const float* gamma = (const float*)d_in[2];
  const float* bnw = (const float*)d_in[3];
  const float* bnb = (const float*)d_in[4];
  float* out = (float*)d_out;

  char* ws = (char*)d_ws;
  float* inv_nx = (float*)ws; ws += (size_t)Bb * Nn * 4;
  float* inv_nt = (float*)ws; ws += (size_t)Bb * Mm * 4;
  bf16* xnT  = (bf16*)ws; ws += (size_t)Bb * Nn * Cch * 2;
  bf16* tgnT = (bf16*)ws; ws += (size_t)Bb * Mm * Cch * 2;
  bf16* xb   = (bf16*)ws; ws += (size_t)Bb * Cch * Nn * 2;
  bf16* S    = (bf16*)ws; ws += (size_t)Bb * Mm * Nn * 2;
  bf16* part = (bf16*)ws; ws += (size_t)SPLITK4 * Bb * Cch * Mm * 2;
  float4* rowp = (float4*)ws; ws += (size_t)Bb * Mm * 16;
  float* bnsum = (float*)ws; ws += (size_t)2 * Cch * 4;
  float* scsh = (float*)ws; ws += (size_t)Cch * 2 * 4;

  zero_bnsum<<<1, 512, 0, stream>>>(bnsum);
  norm_kernel<<<Bb * Nn / 256, 256, 0, stream>>>(x, inv_nx);
  norm_kernel<<<Bb * Mm / 256, 256, 0, stream>>>(tg, inv_nt);
  transpose_scale<<<dim3(Nn / 32, Cch / 32, Bb), dim3(32, 8), 0, stream>>>(x, inv_nx, xnT, xb);
  transpose_scale<<<dim3(Mm / 32, Cch / 32, Bb), dim3(32, 8), 0, stream>>>(tg, inv_nt, tgnT, nullptr);
  // S[b][m][n] = sum_c tgnT[b][m][c] * xnT[b][n][c]  (raw scores, bf16)
  gemm_bt1<<<dim3(Mm / 128, Nn / 128, Bb), 256, 0, stream>>>(tgnT, xnT, S, Mm, Nn, Cch);
  // per-row threshold/denominator (no S rewrite)
  select_topk<<<Bb * Mm / 4, 256, 0, stream>>>(S, rowp);
  // out_part[b][c][m] = sum_n xb[b][c][n] * mask_softmax(S[b][m][n]) — fused
  gemm2_wave<<<dim3(Bb, (Mm / 64) * SPLITK4, 1), 256, 0, stream>>>(xb, S, rowp, part);
  combine_bn<<<Bb * Cch, 256, 0, stream>>>(part, out, bnsum);
  bn_finalize<<<1, 256, 0, stream>>>(bnsum, bnw, bnb, scsh);
  final_kernel<<<2048, 256, 0, stream>>>(out, tg, scsh, gamma);
}

// Round 13
// 198.115 us; speedup vs baseline: 1.1663x; 1.1663x over previous
//
#include <hip/hip_runtime.h>
#include <hip/hip_bf16.h>

#define Bb 8
#define Cch 256
#define Nn 2048
#define Mm 2048
#define KKEEP 1638
#define RANK 410   /* Nn - KKEEP, 0-indexed ascending rank of threshold */
#define HGROUPS 4
#define HPITCH 260 /* 4 sub-hists, 4-bank shift/group: cross-group conflict-free */
#define SPLITK2 2

typedef __hip_bfloat16 bf16;
typedef __attribute__((ext_vector_type(8))) short bf16x8;
typedef __attribute__((ext_vector_type(4))) float f32x4;
typedef unsigned int u32;
typedef unsigned short u16;

__device__ __forceinline__ void gload_lds16(const void* g, void* l) {
  __builtin_amdgcn_global_load_lds((const __attribute__((address_space(1))) u32*)g,
                                   (__attribute__((address_space(3))) u32*)l, 16, 0, 0);
}

// ---------------- norms: inv[b*NN+n] = 1/max(||x[b,:,n]||, 1e-12) ----------
__global__ __launch_bounds__(256) void norm_kernel(const float* __restrict__ t,
                                                   float* __restrict__ inv) {
  int idx = blockIdx.x * 256 + threadIdx.x;          // b*Nn + n
  int b = idx >> 11, n = idx & (Nn - 1);
  const float* p = t + (size_t)b * Cch * Nn + n;
  float s = 0.f;
  #pragma unroll 4
  for (int c = 0; c < Cch; ++c) { float v = p[(size_t)c * Nn]; s += v * v; }
  inv[idx] = 1.f / fmaxf(sqrtf(s), 1e-12f);
}

// ------------- transpose+scale+bf16: out[b][n][c] = bf16(in[b][c][n]*inv[b][n])
// Optionally also emits raw bf16 copy in original [b][c][n] layout (rawb).
__global__ __launch_bounds__(256) void transpose_scale(const float* __restrict__ in,
                                                       const float* __restrict__ inv,
                                                       bf16* __restrict__ outp,
                                                       bf16* __restrict__ rawb) {
  __shared__ float tile[32][33];
  int b = blockIdx.z;
  int n0 = blockIdx.x * 32, c0 = blockIdx.y * 32;
  int tx = threadIdx.x, ty = threadIdx.y;
  const float* src = in + (size_t)b * Cch * Nn;
  #pragma unroll
  for (int i = 0; i < 32; i += 8) {
    float v = src[(size_t)(c0 + ty + i) * Nn + n0 + tx];
    tile[ty + i][tx] = v;
    if (rawb) rawb[(size_t)b * Cch * Nn + (size_t)(c0 + ty + i) * Nn + n0 + tx] = __float2bfloat16(v);
  }
  __syncthreads();
  bf16* dst = outp + (size_t)b * Nn * Cch;
  #pragma unroll
  for (int i = 0; i < 32; i += 8) {
    int n = n0 + ty + i;
    float sc = inv[(b << 11) + n];
    dst[(size_t)n * Cch + c0 + tx] = __float2bfloat16(tile[tx][ty + i] * sc);
  }
}

// ------------- zero the BN accumulator (512 floats) ------------------------
__global__ void zero_bnsum(float* p) { p[threadIdx.x] = 0.f; }

// ------------- gemm1: E = bf16(exp(A * Bt^T)) — exp fused in epilogue ------
// exp is monotone, so downstream top-k on E == top-k on S, and the softmax
// denominator is just sum(E). Moves ALL exp work out of the select kernel.
__global__ __launch_bounds__(256) void gemm_bt1(const bf16* __restrict__ A,
                                                const bf16* __restrict__ Bt,
                                                bf16* __restrict__ Cout,
                                                int Mrows, int Ncols, int K) {
  __shared__ bf16 aT[128 * 32];
  __shared__ bf16 bT[128 * 32];
  const int b = blockIdx.z;
  const int m0 = blockIdx.x * 128;
  const int n0 = blockIdx.y * 128;
  const bf16* Ab = A + (size_t)b * Mrows * K;
  const bf16* Bbp = Bt + (size_t)b * Ncols * K;
  const int tid = threadIdx.x;
  const int lane = tid & 63;
  const int wave = tid >> 6;
  const int wr = wave >> 1, wc = wave & 1;

  f32x4 acc[4][4];
  #pragma unroll
  for (int i = 0; i < 4; i++)
    #pragma unroll
    for (int j = 0; j < 4; j++) acc[i][j] = (f32x4){0.f, 0.f, 0.f, 0.f};

  const int srow = tid >> 2;
  const int scol = (tid & 3) * 8;
  const bf16* gA0 = Ab + (size_t)(m0 + srow) * K + scol;
  const bf16* gB0 = Bbp + (size_t)(n0 + srow) * K + scol;
  bf16* lA = aT + wave * 512;   // wave-uniform LDS base (lane*16B auto-added)
  bf16* lB = bT + wave * 512;

  const int fm = lane & 15;
  const int kb = (lane >> 4) * 8;

  for (int kt = 0; kt < K; kt += 32) {
    gload_lds16(gA0 + kt, lA);
    gload_lds16(gA0 + (size_t)64 * K + kt, lA + 2048);
    gload_lds16(gB0 + kt, lB);
    gload_lds16(gB0 + (size_t)64 * K + kt, lB + 2048);
    __syncthreads();
    bf16x8 af[4], bf_[4];
    #pragma unroll
    for (int mf = 0; mf < 4; mf++)
      af[mf] = *(const bf16x8*)&aT[(wr * 64 + mf * 16 + fm) * 32 + kb];
    #pragma unroll
    for (int nf = 0; nf < 4; nf++)
      bf_[nf] = *(const bf16x8*)&bT[(wc * 64 + nf * 16 + fm) * 32 + kb];
    #pragma unroll
    for (int mf = 0; mf < 4; mf++)
      #pragma unroll
      for (int nf = 0; nf < 4; nf++)
        acc[mf][nf] = __builtin_amdgcn_mfma_f32_16x16x32_bf16(af[mf], bf_[nf], acc[mf][nf], 0, 0, 0);
    __syncthreads();
  }

  const int orow = (lane >> 4) * 4;
  const int ocol = lane & 15;
  bf16* Cb = Cout + (size_t)b * Mrows * Ncols;
  #pragma unroll
  for (int mf = 0; mf < 4; mf++)
    #pragma unroll
    for (int nf = 0; nf < 4; nf++)
      #pragma unroll
      for (int r = 0; r < 4; r++) {
        int gm = m0 + wr * 64 + mf * 16 + orow + r;
        int gn = n0 + wc * 64 + nf * 16 + ocol;
        Cb[(size_t)gm * Ncols + gn] = __float2bfloat16(__expf(acc[mf][nf][r]));
      }
}

// ---- wave-level inclusive scan over 64 lanes ------------------------------
__device__ __forceinline__ u32 wave_incl_scan(u32 v, int lane) {
  #pragma unroll
  for (int off = 1; off < 64; off <<= 1) {
    u32 t = __shfl_up(v, off, 64);
    if (lane >= off) v += t;
  }
  return v;
}

// ------------- per-row top-k MASK over E = exp(S), in place ---------------
// ONE WAVE PER ROW. Pure-integer select: E is positive with a known narrow
// range (E in [0.36,2.9] => bf16 bits u in [0x3EB3,0x4037]), so the 10-bit
// biased key v = clamp(u - 0x3E00, 0, 0x3FF) is monotone in E. Radix:
// pass1 over v>>2 (256 bins, 4-way sub-hists), pass2 over v&3. Masked
// write is a u16 select — no exp, no float packing (exp moved to gemm1).
// Also writes rowinv[row] = 1/sum(E) for the post-GEMM scaling in combine.
__global__ __launch_bounds__(256) void row_topk_mask(bf16* __restrict__ S,
                                                     float* __restrict__ rowinv) {
  const int lane = threadIdx.x & 63;
  const int wv = threadIdx.x >> 6;                 // 0..3
  const int rowIdx = blockIdx.x * 4 + wv;
  bf16* row = S + (size_t)rowIdx * Nn;
  __shared__ u32 hist_s[4][HGROUPS * HPITCH];      // 4 x 4160B
  u32* hist = hist_s[wv];                          // wave-private
  u32* myhist = hist + (lane & (HGROUPS - 1)) * HPITCH;

  // ---- load: slot k holds global elems k*512 + lane*8 .. +7 ----
  uint4 rw[4];
  #pragma unroll
  for (int k = 0; k < 4; k++) rw[k] = ((const uint4*)row)[k * 64 + lane];

  u16 kv[32];
  float se = 0.f;
  #pragma unroll
  for (int k = 0; k < 4; k++) {
    u32 wd[4] = {rw[k].x, rw[k].y, rw[k].z, rw[k].w};
    #pragma unroll
    for (int j = 0; j < 4; j++) {
      u16 a = (u16)(wd[j] & 0xFFFF), b = (u16)(wd[j] >> 16);
      int i0 = k * 8 + 2 * j;
      int va = (int)a - 0x3E00; va = va < 0 ? 0 : (va > 0x3FF ? 0x3FF : va);
      int vb = (int)b - 0x3E00; vb = vb < 0 ? 0 : (vb > 0x3FF ? 0x3FF : vb);
      kv[i0] = (u16)va; kv[i0 + 1] = (u16)vb;
      u32 ba = ((u32)a) << 16, bb = ((u32)b) << 16;
      float fa, fb; __builtin_memcpy(&fa, &ba, 4); __builtin_memcpy(&fb, &bb, 4);
      se += fa + fb;                               // sum of E (denominator)
    }
  }
  #pragma unroll
  for (int off = 32; off > 0; off >>= 1) se += __shfl_xor(se, off, 64);
  if (lane == 0) rowinv[rowIdx] = 1.f / se;

  // ---- radix pass 1: histogram of v>>2 ----
  #pragma unroll
  for (int i = 0; i < 16; i++) hist[i * 64 + lane] = 0;
  if (lane < HGROUPS * HPITCH - 1024) hist[1024 + lane] = 0;
  __threadfence_block();
  #pragma unroll
  for (int i = 0; i < 32; i++) atomicAdd(&myhist[kv[i] >> 2], 1u);
  __threadfence_block();
  u32 h[4], c[4];
  h[0] = h[1] = h[2] = h[3] = 0;
  #pragma unroll
  for (int gg = 0; gg < HGROUPS; gg++) {
    uint4 v = *(const uint4*)&hist[gg * HPITCH + lane * 4];
    h[0] += v.x; h[1] += v.y; h[2] += v.z; h[3] += v.w;
  }
  c[0] = h[0]; c[1] = c[0] + h[1]; c[2] = c[1] + h[2]; c[3] = c[2] + h[3];
  u32 inclTot = wave_incl_scan(c[3], lane);
  u32 pre = inclTot - c[3];                         // exclusive prefix of my 4 bins
  u32 binsel = 0xFFFFFFFFu, belowv = 0;
  #pragma unroll
  for (int i = 0; i < 4; i++) {
    u32 incl = pre + c[i];
    if (incl > (u32)RANK && incl - h[i] <= (u32)RANK) { binsel = lane * 4 + i; belowv = incl - h[i]; }
  }
  unsigned long long mk = __ballot(binsel != 0xFFFFFFFFu);
  int src = __ffsll(mk) - 1;
  u32 b1 = __shfl(binsel, src, 64);
  u32 below = __shfl(belowv, src, 64);

  // ---- radix pass 2: v&3 among keys with v>>2 == b1 ----
  #pragma unroll
  for (int i = 0; i < 16; i++) hist[i * 64 + lane] = 0;
  if (lane < HGROUPS * HPITCH - 1024) hist[1024 + lane] = 0;
  __threadfence_block();
  #pragma unroll
  for (int i = 0; i < 32; i++)
    if ((u32)(kv[i] >> 2) == b1) atomicAdd(&myhist[kv[i] & 3], 1u);
  __threadfence_block();
  h[0] = h[1] = h[2] = h[3] = 0;
  #pragma unroll
  for (int gg = 0; gg < HGROUPS; gg++) {
    uint4 v = *(const uint4*)&hist[gg * HPITCH + lane * 4];
    h[0] += v.x; h[1] += v.y; h[2] += v.z; h[3] += v.w;
  }
  c[0] = h[0]; c[1] = c[0] + h[1]; c[2] = c[1] + h[2]; c[3] = c[2] + h[3];
  inclTot = wave_incl_scan(c[3], lane);
  pre = inclTot - c[3];
  binsel = 0xFFFFFFFFu; u32 totv = 0;
  #pragma unroll
  for (int i = 0; i < 4; i++) {
    u32 incl = below + pre + c[i];
    if (incl > (u32)RANK && incl - h[i] <= (u32)RANK) { binsel = lane * 4 + i; totv = incl; }
  }
  mk = __ballot(binsel != 0xFFFFFFFFu);
  src = __ffsll(mk) - 1;
  u32 lowb = __shfl(binsel, src, 64);               // 0..3 (lane 0's bins)
  u32 totalLE = __shfl(totv, src, 64);              // #keys <= tkey
  u16 tkey = (u16)((b1 << 2) | lowb);
  int keepEq = KKEEP - (Nn - (int)totalLE);         // ties kept, lowest global index first

  // ---- tie ordering: global idx = k*512 + lane*8 + j ----
  int eqk[4];
  #pragma unroll
  for (int k = 0; k < 4; k++) {
    int c2 = 0;
    #pragma unroll
    for (int j = 0; j < 8; j++) c2 += (kv[k * 8 + j] == tkey);
    eqk[k] = c2;
  }
  int eqbase[4]; int running = 0;
  #pragma unroll
  for (int k = 0; k < 4; k++) {
    u32 inclL = wave_incl_scan((u32)eqk[k], lane);
    int waveTot = __shfl((int)inclL, 63, 64);
    eqbase[k] = running + (int)inclL - eqk[k];
    running += waveTot;
  }

  // ---- masked write: keep iff v > tkey, or v == tkey and order < keepEq ---
  #pragma unroll
  for (int k = 0; k < 4; k++) {
    int eqs = eqbase[k];
    u32 wd[4] = {rw[k].x, rw[k].y, rw[k].z, rw[k].w};
    u32 od[4];
    #pragma unroll
    for (int j = 0; j < 4; j++) {
      u16 a = (u16)(wd[j] & 0xFFFF), b = (u16)(wd[j] >> 16);
      int i0 = k * 8 + 2 * j;
      u16 o0 = 0, o1 = 0;
      if (kv[i0] > tkey) o0 = a;
      else if (kv[i0] == tkey) { if (eqs < keepEq) o0 = a; eqs++; }
      if (kv[i0 + 1] > tkey) o1 = b;
      else if (kv[i0 + 1] == tkey) { if (eqs < keepEq) o1 = b; eqs++; }
      od[j] = (u32)o0 | ((u32)o1 << 16);
    }
    uint4 outv = {od[0], od[1], od[2], od[3]};
    ((uint4*)row)[k * 64 + lane] = outv;
  }
}

// ------------- WAVE-ASYNC gemm2: part = xb * Emask^T, split-K partials -----
// Each wave owns an independent 32x64 output tile with PRIVATE LDS slices
// (A 32x32, own copy of B 64x32). Per K-step: 6x global_load_lds ->
// s_waitcnt vmcnt(0) (per-wave counter; NO barrier, no wave convoy) ->
// 8 MFMA. Waves interleave memory waits freely across the SIMD.
// Grid (8, numTiles*SPLITK2): blockIdx.x = batch pins each batch to one XCD.
__global__ __launch_bounds__(256) void gemm2_wave(const bf16* __restrict__ A,
                                                  const bf16* __restrict__ Bt,
                                                  float* __restrict__ part) {
  constexpr int KS = Nn / SPLITK2;           // 1024 K per slice
  constexpr int NT = KS / 32;                // 32 steps
  constexpr int numTiles = (Cch / 128) * (Mm / 64);   // 64
  __shared__ bf16 aW[4][32 * 32];
  __shared__ bf16 bW[4][64 * 32];
  const int b = blockIdx.x;                  // XCD = dispatch_id % 8 = batch
  int yy = blockIdx.y;
  int tile = yy % numTiles, ks = yy / numTiles;
  int m0 = (tile % (Cch / 128)) * 128;       // m fastest: siblings adjacent
  int n0 = (tile / (Cch / 128)) * 64;
  const bf16* Ab = A + (size_t)b * Cch * Nn;
  const bf16* Bbp = Bt + (size_t)b * Mm * Nn;
  const int lane = threadIdx.x & 63;
  const int w = threadIdx.x >> 6;
  const int srow = lane >> 2;                // 16 rows per gload
  const int scol = (lane & 3) * 8;
  const int kBeg = ks * KS;
  const bf16* gA = Ab + (size_t)(m0 + w * 32 + srow) * Nn + kBeg + scol;
  const bf16* gB = Bbp + (size_t)(n0 + srow) * Nn + kBeg + scol;
  const int fm = lane & 15;
  const int kb = (lane >> 4) * 8;

  f32x4 acc[2][4];
  #pragma unroll
  for (int i = 0; i < 2; i++)
    #pragma unroll
    for (int j = 0; j < 4; j++) acc[i][j] = (f32x4){0.f, 0.f, 0.f, 0.f};

  bf16* lA = &aW[w][0];                      // wave-uniform LDS bases
  bf16* lB = &bW[w][0];

  for (int t = 0; t < NT; ++t) {
    int kt = t * 32;
    gload_lds16(gA + kt, lA);
    gload_lds16(gA + (size_t)16 * Nn + kt, lA + 16 * 32);
    #pragma unroll
    for (int i = 0; i < 4; i++)
      gload_lds16(gB + (size_t)(i * 16) * Nn + kt, lB + i * 16 * 32);
    asm volatile("s_waitcnt vmcnt(0)" ::: "memory");
    bf16x8 af[2], bf_[4];
    #pragma unroll
    for (int mf = 0; mf < 2; mf++)
      af[mf] = *(const bf16x8*)&aW[w][(mf * 16 + fm) * 32 + kb];
    #pragma unroll
    for (int nf = 0; nf < 4; nf++)
      bf_[nf] = *(const bf16x8*)&bW[w][(nf * 16 + fm) * 32 + kb];
    #pragma unroll
    for (int mf = 0; mf < 2; mf++)
      #pragma unroll
      for (int nf = 0; nf < 4; nf++)
        acc[mf][nf] = __builtin_amdgcn_mfma_f32_16x16x32_bf16(af[mf], bf_[nf], acc[mf][nf], 0, 0, 0);
  }

  const int orow = (lane >> 4) * 4;
  const int ocol = lane & 15;
  float* Pf = part + (size_t)ks * Bb * Cch * Mm + (size_t)b * Cch * Mm;
  #pragma unroll
  for (int mf = 0; mf < 2; mf++)
    #pragma unroll
    for (int nf = 0; nf < 4; nf++)
      #pragma unroll
      for (int r = 0; r < 4; r++) {
        int gm = m0 + w * 32 + mf * 16 + orow + r;
        int gn = n0 + nf * 16 + ocol;
        Pf[(size_t)gm * Mm + gn] = acc[mf][nf][r];
      }
}

// ------------- combine split-K: *inv[m], leaky, BN stats, out --------------
__global__ __launch_bounds__(256) void combine_bn(const float* __restrict__ part,
                                                  const float* __restrict__ rowinv,
                                                  float* __restrict__ outp,
                                                  float* __restrict__ bnsum) {
  int bc = blockIdx.x;                       // b*Cch + c
  int b = bc >> 8;
  const float4* p0 = (const float4*)(part + (size_t)bc * Mm);
  const float4* p1 = (const float4*)(part + (size_t)Bb * Cch * Mm + (size_t)bc * Mm);
  const float4* iv = (const float4*)(rowinv + (size_t)b * Mm);
  float4* po = (float4*)(outp + (size_t)bc * Mm);
  int tid = threadIdx.x;
  float s = 0.f, ss = 0.f;
  #pragma unroll
  for (int i = 0; i < 2; i++) {
    int idx = tid + i * 256;                 // 512 float4 per row
    float4 a = p0[idx], cdd = p1[idx], w = iv[idx];
    float4 v;
    v.x = (a.x + cdd.x) * w.x; v.y = (a.y + cdd.y) * w.y;
    v.z = (a.z + cdd.z) * w.z; v.w = (a.w + cdd.w) * w.w;
    v.x = v.x >= 0.f ? v.x : 0.01f * v.x;
    v.y = v.y >= 0.f ? v.y : 0.01f * v.y;
    v.z = v.z >= 0.f ? v.z : 0.01f * v.z;
    v.w = v.w >= 0.f ? v.w : 0.01f * v.w;
    po[idx] = v;
    s += v.x + v.y + v.z + v.w;
    ss += v.x * v.x + v.y * v.y + v.z * v.z + v.w * v.w;
  }
  __shared__ float r1[256], r2[256];
  r1[tid] = s; r2[tid] = ss; __syncthreads();
  for (int k = 128; k > 0; k >>= 1) {
    if (tid < k) { r1[tid] += r1[tid + k]; r2[tid] += r2[tid + k]; }
    __syncthreads();
  }
  if (tid == 0) {
    int c = bc & (Cch - 1);
    atomicAdd(&bnsum[c], r1[0]);
    atomicAdd(&bnsum[Cch + c], r2[0]);
  }
}

// ------------- BN finalize: scale/shift per channel ------------------------
__global__ __launch_bounds__(256) void bn_finalize(const float* __restrict__ bnsum,
                                                   const float* __restrict__ bnw,
                                                   const float* __restrict__ bnb,
                                                   float* __restrict__ scsh) {
  int c = threadIdx.x;
  float cnt = (float)(Bb * Mm);
  float mean = bnsum[c] / cnt;
  float var = bnsum[Cch + c] / cnt - mean * mean;
  float scale = bnw[c] / sqrtf(var + 1e-5f);
  scsh[c * 2] = scale;
  scsh[c * 2 + 1] = bnb[c] - mean * scale;
}

// ------------- final: out = (y*scale+shift)*gamma + tg --------------------
__global__ __launch_bounds__(256) void final_kernel(float* io, const float* __restrict__ tg,
                                                    const float* __restrict__ scsh,
                                                    const float* __restrict__ gamma) {
  size_t n4 = (size_t)Bb * Cch * Mm / 4;
  float g = gamma[0];
  size_t stride = (size_t)gridDim.x * 256;
  for (size_t i = (size_t)blockIdx.x * 256 + threadIdx.x; i < n4; i += stride) {
    int c = (int)((i * 4 / Mm) % Cch);
    float4 v = ((const float4*)io)[i];
    float4 t = ((const float4*)tg)[i];
    float sc = scsh[c * 2], sh = scsh[c * 2 + 1];
    v.x = (v.x * sc + sh) * g + t.x;
    v.y = (v.y * sc + sh) * g + t.y;
    v.z = (v.z * sc + sh) * g + t.z;
    v.w = (v.w * sc + sh) * g + t.w;
    ((float4*)io)[i] = v;
  }
}

extern "C" void kernel_launch(void* const* d_in, const int* in_sizes, int n_in,
                              void* d_out, int out_size, void* d_ws, size_t ws_size,
                              hipStream_t stream) {
  (void)in_sizes; (void)n_in; (void)out_size; (void)ws_size;
  const float* x   = (const float*)d_in[0];
  const float* tg  = (const float*)d_in[1];
  const float* gamma = (const float*)d_in[2];
  const float* bnw = (const float*)d_in[3];
  const float* bnb = (const float*)d_in[4];
  float* out = (float*)d_out;

  char* ws = (char*)d_ws;
  float* inv_nx = (float*)ws; ws += (size_t)Bb * Nn * 4;
  float* inv_nt = (float*)ws; ws += (size_t)Bb * Mm * 4;
  bf16* xnT  = (bf16*)ws; ws += (size_t)Bb * Nn * Cch * 2;
  bf16* tgnT = (bf16*)ws; ws += (size_t)Bb * Mm * Cch * 2;
  bf16* xb   = (bf16*)ws; ws += (size_t)Bb * Cch * Nn * 2;
  bf16* S    = (bf16*)ws; ws += (size_t)Bb * Mm * Nn * 2;   // holds E = exp(S)
  float* part = (float*)ws; ws += (size_t)SPLITK2 * Bb * Cch * Mm * 4;
  float* rowinv = (float*)ws; ws += (size_t)Bb * Mm * 4;
  float* bnsum = (float*)ws; ws += (size_t)2 * Cch * 4;
  float* scsh = (float*)ws; ws += (size_t)Cch * 2 * 4;

  zero_bnsum<<<1, 512, 0, stream>>>(bnsum);
  norm_kernel<<<Bb * Nn / 256, 256, 0, stream>>>(x, inv_nx);
  norm_kernel<<<Bb * Mm / 256, 256, 0, stream>>>(tg, inv_nt);
  transpose_scale<<<dim3(Nn / 32, Cch / 32, Bb), dim3(32, 8), 0, stream>>>(x, inv_nx, xnT, xb);
  transpose_scale<<<dim3(Mm / 32, Cch / 32, Bb), dim3(32, 8), 0, stream>>>(tg, inv_nt, tgnT, nullptr);
  // E[b][m][n] = exp( sum_c tgnT[b][m][c] * xnT[b][n][c] )
  gemm_bt1<<<dim3(Mm / 128, Nn / 128, Bb), 256, 0, stream>>>(tgnT, xnT, S, Mm, Nn, Cch);
  // in-place top-k mask on E + rowinv = 1/sum(E)
  row_topk_mask<<<Bb * Mm / 4, 256, 0, stream>>>(S, rowinv);
  // part[b][c][m] = sum_n xb[b][c][n] * Emask[b][m][n]  (wave-async, split-K)
  gemm2_wave<<<dim3(Bb, (Cch / 128) * (Mm / 64) * SPLITK2, 1), 256, 0, stream>>>(xb, S, part);
  combine_bn<<<Bb * Cch, 256, 0, stream>>>(part, rowinv, out, bnsum);
  bn_finalize<<<1, 256, 0, stream>>>(bnsum, bnw, bnb, scsh);
  final_kernel<<<2048, 256, 0, stream>>>(out, tg, scsh, gamma);
}